// Round 7
// baseline (162.744 us; speedup 1.0000x reference)
//
#include <hip/hip_runtime.h>
#include <math.h>

#define NS   16
#define HH   512
#define WW   512
#define HW   (HH*WW)
#define TOPK 13107
#define NBIN 1024

// ---- ws word offsets. NO ATOMICS EVER TARGET d_ws (measured 100+us stalls r1/r2).
// ---- NO cooperative/persistent kernel (measured 1.1ms effective 263 GB/s, r5).
// ---- NO ballot-leader aggregation for smooth value-domain bins (r6: 157us k_dark).
// ---- NO multi-word/float same-address LDS atomics per pixel (r9: 125us k_dark).
// ---- Block-count halving EXHAUSTED at r3 point (r4: +4.8us regression).
// ---- XCD swizzle PROVEN (r5: -6.8us). T14 channel prefetch ~neutral (r6: -0.6us, kept).
// ---- This round: k_main hb-array ELIMINATED — full separable 5x5 blur per
//      thread in registers (6 rows x 3 f4 xs reads, ~2.5x redundant h-blur FMA
//      at 4% VALUBusy = free). Barriers 9->6/block, LDS 20.2->10.9 KB.
#define O_O1   0        // [16][7] squashed o1 params   (written k_dark, read k_main)
#define O_O2   112      // [16][4] softmax weights
#define O_DEN  176      // [16]    sum(o2)+0.001
#define O_KN   304      // [16]    remaining k within threshold bin
#define O_MMP  512      // [48][512] per-tile min(0:128)/max(256:384) partials
#define O_PART 25088    // [512][8] asum per-block partials (plain stores only)
#define O_DARK 33280    // [16*512*512] f32 dark channel

// ---- d_out scratch (words; consumed by k_asum before k_main overwrites out):
//   hist = out + 16HW  (16x1024 u32; atomics OK here — d_out, measured fast r2-r4)

// Gaussian weights phi/(sum+0.001), hardcoded (double-derived; ref fp32 diff ~1e-8)
#define G0 0.054466787f
#define G1 0.244103071f
#define G2 0.402457854f

__device__ __forceinline__ float tanh01(float v) { return tanhf(v)*0.5f + 0.5f; }
__device__ __forceinline__ float clamp01(float v) { return fminf(fmaxf(v, 0.0f), 1.0f); }
__device__ __forceinline__ int dark_bin(float v) {
  int b = (int)(v * (float)NBIN);
  return b > (NBIN-1) ? (NBIN-1) : (b < 0 ? 0 : b);
}

// halo load for k_main staging: task i covers xs row i/18, col-quad i%18
__device__ __forceinline__ float4 ld_halo(const float* __restrict__ xc, int i,
                                          int h0, int w0, bool interior) {
  int rr = i / 18, q = i - rr*18;
  int gh = h0 - 2 + rr, gw = w0 - 4 + 4*q;
  if (interior) return *(const float4*)&xc[(size_t)gh*WW + gw];
  float4 v; v.x = 0.f; v.y = 0.f; v.z = 0.f; v.w = 0.f;
  if (gh >= 0 && gh < HH && gw >= 0 && gw < WW)
    v = *(const float4*)&xc[(size_t)gh*WW + gw];
  return v;
}

// ---------------- fused minc + 15x15 box filter + count histogram ----------------
// 1024 blocks (XCD-swizzled), 512 threads: 64x64 dark tile.
__global__ void __launch_bounds__(512)
k_dark(const float* __restrict__ x, float* __restrict__ wsf, unsigned* __restrict__ hist,
       const float* __restrict__ o1, const float* __restrict__ o2) {
  __shared__ __align__(16) float sm[6240 + 78*64];   // union(minc[78*80], lh[1024*4]) + hsum[4992]
  float* minc = sm;
  unsigned* lh = (unsigned*)sm;     // [1024 bins][4 replicas] interleaved
  float* hsum = sm + 6240;
  int tid = threadIdx.x;
  // bijective XCD swizzle (1024 blocks, 8 XCDs -> 128-block contiguous chunks;
  // 128 blocks = 2 full samples of 64 tiles -> same-sample halos L2-local)
  int swz = (blockIdx.x & 7) * 128 + (blockIdx.x >> 3);
  int n = swz >> 6, rem = swz & 63;
  int w0 = (rem & 7) * 64, h0 = (rem >> 3) * 64;
  const float* xb = x + (size_t)n*3*HW;

  // param squashing (one block per sample; hidden under staging; read by k_main)
  if (rem == 0 && tid == 0) {
    wsf[O_O1+n*7+0] = tanh01(o1[n*7+0])*0.25f + 1.0f;
    wsf[O_O1+n*7+1] = tanh01(o1[n*7+1])*0.9f  + 0.1f;
    wsf[O_O1+n*7+2] = tanh01(o1[n*7+2])*2.0f;
    wsf[O_O1+n*7+3] = tanh01(o1[n*7+3]);
    wsf[O_O1+n*7+4] = tanh01(o1[n*7+4])*0.1f + 0.95f;
    wsf[O_O1+n*7+5] = tanh01(o1[n*7+5])*0.1f + 0.95f;
    wsf[O_O1+n*7+6] = tanh01(o1[n*7+6])*0.1f + 0.95f;
    float q0 = expf(tanh01(o2[n*4+0]));
    float q1 = expf(tanh01(o2[n*4+1]));
    float q2 = expf(tanh01(o2[n*4+2]));
    float q3 = expf(tanh01(o2[n*4+3]));
    float s = q0+q1+q2+q3;
    q0 /= s; q1 /= s; q2 /= s; q3 /= s;
    wsf[O_O2+n*4+0]=q0; wsf[O_O2+n*4+1]=q1; wsf[O_O2+n*4+2]=q2; wsf[O_O2+n*4+3]=q3;
    wsf[O_DEN+n] = (q0+q1+q2+q3) + 0.001f;
  }

  // stage minc rows [h0-7,h0+71) cols [w0-8,w0+72), zero outside (box filter zero-pads)
  bool interior = (w0 >= 8) && (w0 + 72 <= WW) && (h0 >= 7) && (h0 + 71 <= HH);
  if (interior) {
    for (int i = tid; i < 78*20; i += 512) {
      int r = i / 20, q = i - r*20;
      size_t o = (size_t)(h0 - 7 + r)*WW + (w0 - 8 + 4*q);
      float4 a = *(const float4*)&xb[o];
      float4 b = *(const float4*)&xb[HW + o];
      float4 c = *(const float4*)&xb[2*HW + o];
      float4 v;
      v.x = fminf(fminf(a.x,b.x),c.x); v.y = fminf(fminf(a.y,b.y),c.y);
      v.z = fminf(fminf(a.z,b.z),c.z); v.w = fminf(fminf(a.w,b.w),c.w);
      *(float4*)&minc[r*80 + 4*q] = v;
    }
  } else {
    for (int i = tid; i < 78*20; i += 512) {
      int r = i / 20, q = i - r*20;
      int hm = h0 - 7 + r, wc = w0 - 8 + 4*q;
      float4 v; v.x = 0.f; v.y = 0.f; v.z = 0.f; v.w = 0.f;
      if (hm >= 0 && hm < HH && wc >= 0 && wc < WW) {
        size_t o = (size_t)hm*WW + wc;
        float4 a = *(const float4*)&xb[o];
        float4 b = *(const float4*)&xb[HW + o];
        float4 c = *(const float4*)&xb[2*HW + o];
        v.x = fminf(fminf(a.x,b.x),c.x); v.y = fminf(fminf(a.y,b.y),c.y);
        v.z = fminf(fminf(a.z,b.z),c.z); v.w = fminf(fminf(a.w,b.w),c.w);
      }
      *(float4*)&minc[r*80 + 4*q] = v;
    }
  }
  __syncthreads();
  // horizontal 15-tap sum
  for (int i = tid; i < 78*16; i += 512) {
    int r = i >> 4, c4 = (i & 15) * 4;
    const float4* mr = (const float4*)&minc[r*80];
    int qb = c4 >> 2;
    float m[20];
    #pragma unroll
    for (int t = 0; t < 5; ++t) {
      float4 v = mr[qb + t];
      m[4*t] = v.x; m[4*t+1] = v.y; m[4*t+2] = v.z; m[4*t+3] = v.w;
    }
    float s = 0.f;
    #pragma unroll
    for (int j = 1; j <= 15; ++j) s += m[j];
    float4 o;
    o.x = s; s += m[16] - m[1];
    o.y = s; s += m[17] - m[2];
    o.z = s; s += m[18] - m[3];
    o.w = s;
    *(float4*)&hsum[r*64 + c4] = o;
  }
  __syncthreads();
  {
    uint4 z4; z4.x = 0u; z4.y = 0u; z4.z = 0u; z4.w = 0u;
    for (int i = tid; i < NBIN; i += 512) ((uint4*)lh)[i] = z4;  // minc dead; reuse
  }
  __syncthreads();
  // vertical 15-tap sliding sum -> dark; run-length + 4-replica LDS atomics
  {
    int c = tid & 63, ty = tid >> 6, r0 = ty * 8;
    int rep = tid & 3;
    float s = 0.f;
    #pragma unroll
    for (int j = 0; j < 15; ++j) s += hsum[(r0 + j)*64 + c];
    float* dk = wsf + O_DARK + (size_t)n*HW;
    int prevb = -1; unsigned cnt = 0;
    #pragma unroll
    for (int i = 0; i < 8; ++i) {
      int r = r0 + i;
      float v = s * (1.0f/225.0f);
      dk[(size_t)(h0 + r)*WW + w0 + c] = v;
      int b = dark_bin(v);
      if (b == prevb) { cnt++; }
      else {
        if (cnt) atomicAdd(&lh[(prevb << 2) | rep], cnt);
        prevb = b; cnt = 1u;
      }
      if (i < 7) s += hsum[(r + 15)*64 + c] - hsum[r*64 + c];
    }
    atomicAdd(&lh[(prevb << 2) | rep], cnt);
  }
  __syncthreads();
  unsigned* gh = hist + n*NBIN;
  for (int b = tid; b < NBIN; b += 512) {
    unsigned v = lh[4*b] + lh[4*b+1] + lh[4*b+2] + lh[4*b+3];
    if (v) atomicAdd(&gh[b], v);
  }
}

// ---------------- fused select head + atmospheric partial sums ----------------
// 512 blocks (XCD-swizzled): 32 chunks x 8192 px per sample.
__global__ void __launch_bounds__(256)
k_asum(const float* __restrict__ x, float* __restrict__ wsf,
       const unsigned* __restrict__ hist, unsigned* __restrict__ wsu) {
  __shared__ __align__(16) unsigned lh[NBIN];
  __shared__ unsigned spp[256];
  __shared__ unsigned wtot[4];
  __shared__ int sh_bsel;
  __shared__ unsigned sh_kn;
  __shared__ float bl[4][7];
  int tid = threadIdx.x;
  int lane = tid & 63, wave = tid >> 6;
  // bijective XCD swizzle (512 blocks -> 64-block chunks = 2 samples per XCD)
  int swz = (blockIdx.x & 7) * 64 + (blockIdx.x >> 3);
  int n = swz >> 5, chunk = swz & 31;
  // select head: load hist (L2-hot) + redundant per-block parallel scan
  {
    uint4 v = ((const uint4*)(hist + n*NBIN))[tid];   // 4 bins per thread
    *(uint4*)&lh[tid*4] = v;
    spp[tid] = v.x + v.y + v.z + v.w;
  }
  __syncthreads();
  // wave-level inclusive suffix scan of spp (suffix = sum over t' >= t)
  unsigned sv = spp[tid];
  #pragma unroll
  for (int off = 1; off < 64; off <<= 1) {
    unsigned u = __shfl_down(sv, off);
    if (lane + off < 64) sv += u;
  }
  if (lane == 0) wtot[wave] = sv;
  __syncthreads();
  unsigned above = 0;
  #pragma unroll
  for (int w2 = 1; w2 < 4; ++w2) above += (wave + w2 < 4) ? wtot[wave + w2] : 0u;
  unsigned S = sv + above;            // inclusive suffix sum at tid
  unsigned Snext = S - spp[tid];      // suffix sum at tid+1
  if (S >= (unsigned)TOPK && Snext < (unsigned)TOPK) {   // unique crossing thread
    unsigned cum = Snext;             // count of pixels in groups above
    int bsel = tid*4;
    for (int b = tid*4 + 3; b >= tid*4; --b) {
      if (cum + lh[b] >= (unsigned)TOPK) { bsel = b; break; }
      cum += lh[b];
    }
    sh_bsel = bsel;
    sh_kn = (unsigned)TOPK - cum;
  }
  __syncthreads();
  int bsel = sh_bsel;
  if (tid == 0 && chunk == 0) wsu[O_KN + n] = sh_kn;   // plain store to ws
  // partial sums over this 8192-element chunk; x loads PREDICATED on dark bin
  // (dark is 15x15-box smooth -> selected ~5% clustered -> most waves skip via execz)
  const float4* db = (const float4*)(wsf + O_DARK + (size_t)n*HW) + (size_t)chunk*2048;
  const float4* x0 = (const float4*)(x + (size_t)n*3*HW) + (size_t)chunk*2048;
  const float4* x1 = x0 + HW/4;
  const float4* x2 = x0 + HW/2;
  float s0=0,s1=0,s2=0,e0=0,e1=0,e2=0,ec=0;
  #pragma unroll
  for (int k = 0; k < 8; ++k) {
    int idx = k*256 + tid;
    float4 d = db[idx];
    int bbx = dark_bin(d.x), bby = dark_bin(d.y);
    int bbz = dark_bin(d.z), bbw = dark_bin(d.w);
    int bmax = bbx > bby ? bbx : bby;
    bmax = bbz > bmax ? bbz : bmax;
    bmax = bbw > bmax ? bbw : bmax;
    if (bmax >= bsel) {
      float4 a = x0[idx], b = x1[idx], c = x2[idx];
      #define ACC(BB, AX, BX, CX) { \
        bool gt = (BB > bsel), eq = (BB == bsel); \
        s0 += gt ? AX : 0.f; s1 += gt ? BX : 0.f; s2 += gt ? CX : 0.f; \
        e0 += eq ? AX : 0.f; e1 += eq ? BX : 0.f; e2 += eq ? CX : 0.f; \
        ec += eq ? 1.f : 0.f; }
      ACC(bbx, a.x, b.x, c.x) ACC(bby, a.y, b.y, c.y)
      ACC(bbz, a.z, b.z, c.z) ACC(bbw, a.w, b.w, c.w)
      #undef ACC
    }
  }
  #pragma unroll
  for (int off = 32; off; off >>= 1) {
    s0 += __shfl_down(s0, off); s1 += __shfl_down(s1, off); s2 += __shfl_down(s2, off);
    e0 += __shfl_down(e0, off); e1 += __shfl_down(e1, off); e2 += __shfl_down(e2, off);
    ec += __shfl_down(ec, off);
  }
  if (lane == 0) {
    bl[wave][0]=s0; bl[wave][1]=s1; bl[wave][2]=s2;
    bl[wave][3]=e0; bl[wave][4]=e1; bl[wave][5]=e2; bl[wave][6]=ec;
  }
  __syncthreads();
  if (tid < 7) wsf[O_PART + (size_t)swz*8 + tid] =
      bl[0][tid] + bl[1][tid] + bl[2][tid] + bl[3][tid];   // plain store to ws
}

// ---------------- fused per-pixel kernel: 64x32 tile, 2 rows/thread ----------------
// 2048 blocks (XCD-swizzled), 256 threads. No hb array: each thread computes
// the separable 5x5 blur for its 2 rows directly from xs (6 rows x 3 f4 reads,
// h-blur recomputed in registers). 2 barriers/channel. T14 prefetch kept.
__global__ void __launch_bounds__(256)
k_main(const float* __restrict__ x, float* __restrict__ wsf,
       const unsigned* __restrict__ wsu, float* __restrict__ out) {
  __shared__ __align__(16) float xs[36*76];   // rows h0-2..h0+33, cols w0-4..w0+67, stride 76
  __shared__ float rmn[4], rmx[4];
  __shared__ float shA[3];
  int tid = threadIdx.x;
  // bijective XCD swizzle (2048 blocks -> 256-block chunks = 2 samples per XCD)
  int swz = (blockIdx.x & 7) * 256 + (blockIdx.x >> 3);
  int n = swz >> 7, bxy = swz & 127;           // [0,128)
  int w0 = (bxy & 7) * 64, h0 = (bxy >> 3) * 32;
  int r2 = tid >> 4, c4 = (tid & 15) * 4;      // thread owns rows 2r2, 2r2+1
  int wave = tid >> 6, lane = tid & 63;
  const float* dkp = wsf + O_DARK + (size_t)n*HW + (size_t)(h0 + 2*r2)*WW + w0 + c4;
  float4 dk0 = *(const float4*)dkp;
  float4 dk1 = *(const float4*)(dkp + WW);
  float param = wsf[O_O1 + n*7 + 0];
  float lamda = wsf[O_O1 + n*7 + 2];
  float wpar  = wsf[O_O1 + n*7 + 3];
  float wbc[3];
  wbc[0] = wsf[O_O1 + n*7 + 4];
  wbc[1] = wsf[O_O1 + n*7 + 5];
  wbc[2] = wsf[O_O1 + n*7 + 6];
  float q0 = wsf[O_O2 + n*4 + 0], q1 = wsf[O_O2 + n*4 + 1];
  float q2 = wsf[O_O2 + n*4 + 2], q3 = wsf[O_O2 + n*4 + 3];
  float rden = 1.0f / wsf[O_DEN + n];
  bool interior = (w0 >= 4) && (w0 + 68 <= WW) && (h0 >= 2) && (h0 + 34 <= HH);
  // A-reduce head (once per block, all 3 channels; 32 partial-sets from k_asum)
  if (tid < 64) {
    float s0=0,s1=0,s2=0,e0=0,e1=0,e2=0,ec=0;
    if (tid < 32) {
      const float* p = wsf + O_PART + (size_t)(n*32 + tid)*8;
      s0=p[0]; s1=p[1]; s2=p[2]; e0=p[3]; e1=p[4]; e2=p[5]; ec=p[6];
    }
    #pragma unroll
    for (int off = 32; off; off >>= 1) {
      s0 += __shfl_down(s0, off); s1 += __shfl_down(s1, off); s2 += __shfl_down(s2, off);
      e0 += __shfl_down(e0, off); e1 += __shfl_down(e1, off); e2 += __shfl_down(e2, off);
      ec += __shfl_down(ec, off);
    }
    if (tid == 0) {
      float kn = (float)wsu[O_KN + n];
      float ce = fmaxf(ec, 1.0f);
      shA[0] = (s0 + kn * (e0 / ce)) * (1.0f/(float)TOPK);
      shA[1] = (s1 + kn * (e1 / ce)) * (1.0f/(float)TOPK);
      shA[2] = (s2 + kn * (e2 / ce)) * (1.0f/(float)TOPK);
    }
  }

  // staging register set (648 tasks: tid, tid+256, tid+512 if tid<136)
  float4 pf0, pf1, pf2;
  #define LOADCH(cc) do { \
    const float* xc = x + (size_t)(n*3 + (cc))*HW; \
    pf0 = ld_halo(xc, tid,       h0, w0, interior); \
    pf1 = ld_halo(xc, tid + 256, h0, w0, interior); \
    if (tid < 136) pf2 = ld_halo(xc, tid + 512, h0, w0, interior); \
  } while (0)
  #define STORECH() do { \
    { int rr = tid/18, q = tid - rr*18; *(float4*)&xs[rr*76 + 4*q] = pf0; } \
    { int i2 = tid + 256; int rr = i2/18, q = i2 - rr*18; *(float4*)&xs[rr*76 + 4*q] = pf1; } \
    if (tid < 136) { int i2 = tid + 512; int rr = i2/18, q = i2 - rr*18; *(float4*)&xs[rr*76 + 4*q] = pf2; } \
  } while (0)

  // prologue: stage channel 0
  LOADCH(0);
  STORECH();
  __syncthreads();   // xs(c0) ready; also covers shA write

  int qb = c4 >> 2;
  for (int c = 0; c < 3; ++c) {
    int z = n*3 + c;
    // issue next channel's staging loads (latency hides under blur+pixel phase)
    if (c < 2) LOADCH(c + 1);
    // register separable blur: rows 2r2..2r2+5 of xs, h-blur on the fly.
    // output row a (=2r2) taps h-rows 0..4; row b (=2r2+1) taps 1..5.
    float4 acc0, acc1;
    acc0.x = acc0.y = acc0.z = acc0.w = 0.f;
    acc1.x = acc1.y = acc1.z = acc1.w = 0.f;
    const float cA[6] = {G0, G1, G2, G1, G0, 0.f};
    const float cB[6] = {0.f, G0, G1, G2, G1, G0};
    #pragma unroll
    for (int k = 0; k < 6; ++k) {
      const float4* xr = (const float4*)&xs[(2*r2 + k)*76];
      float4 A4 = xr[qb], B4 = xr[qb+1], C4 = xr[qb+2];
      float m2=A4.z, m3=A4.w, m4=B4.x, m5=B4.y, m6=B4.z, m7=B4.w, m8=C4.x, m9=C4.y;
      float4 h;
      h.x = G0*(m2+m6) + G1*(m3+m5) + G2*m4;
      h.y = G0*(m3+m7) + G1*(m4+m6) + G2*m5;
      h.z = G0*(m4+m8) + G1*(m5+m7) + G2*m6;
      h.w = G0*(m5+m9) + G1*(m6+m8) + G2*m7;
      float wa = cA[k], wb2 = cB[k];
      acc0.x += wa*h.x; acc0.y += wa*h.y; acc0.z += wa*h.z; acc0.w += wa*h.w;
      acc1.x += wb2*h.x; acc1.y += wb2*h.y; acc1.z += wb2*h.z; acc1.w += wb2*h.w;
    }
    float wb = wbc[c];
    float A  = shA[c];
    float4 xv0 = *(const float4*)&xs[(2*r2+2)*76 + c4 + 4];
    float4 xv1 = *(const float4*)&xs[(2*r2+3)*76 + c4 + 4];
    float4 os0, os1;
    float mnv = 3.4e38f, mxv = -3.4e38f;
    #define PIX(OX, XV, BL, DK) { \
      float blur = clamp01(BL); \
      float x4v = clamp01(XV + lamda*(XV - blur)); \
      float x1v = clamp01(XV * wb); \
      float x2v = clamp01(__expf(param*__logf(XV)) + 0.001f); \
      float tr = 1.0f - wpar*DK; tr = tr > 0.1f ? tr : 0.1f; \
      float x5v = clamp01((XV - A) * __builtin_amdgcn_rcpf(tr + 0.001f) + A); \
      OX = (XV + 0.1f*(q0*x1v + q1*x2v + q2*x4v + q3*x5v)) * rden; \
      mnv = fminf(mnv, OX); mxv = fmaxf(mxv, OX); }
    PIX(os0.x, xv0.x, acc0.x, dk0.x)
    PIX(os0.y, xv0.y, acc0.y, dk0.y)
    PIX(os0.z, xv0.z, acc0.z, dk0.z)
    PIX(os0.w, xv0.w, acc0.w, dk0.w)
    PIX(os1.x, xv1.x, acc1.x, dk1.x)
    PIX(os1.y, xv1.y, acc1.y, dk1.y)
    PIX(os1.z, xv1.z, acc1.z, dk1.z)
    PIX(os1.w, xv1.w, acc1.w, dk1.w)
    #undef PIX
    float* op = out + (size_t)z*HW + (size_t)(h0 + 2*r2)*WW + w0 + c4;
    *(float4*)op = os0;
    *(float4*)(op + WW) = os1;
    #pragma unroll
    for (int off = 32; off; off >>= 1) {
      mnv = fminf(mnv, __shfl_down(mnv, off));
      mxv = fmaxf(mxv, __shfl_down(mxv, off));
    }
    if (lane == 0) { rmn[wave] = mnv; rmx[wave] = mxv; }
    __syncthreads();   // all xs reads done; rmn/rmx visible
    if (tid == 0) {
      mnv = fminf(fminf(rmn[0], rmn[1]), fminf(rmn[2], rmn[3]));
      mxv = fmaxf(fmaxf(rmx[0], rmx[1]), fmaxf(rmx[2], rmx[3]));
      wsf[O_MMP + z*512 + bxy]       = mnv;   // plain stores to ws
      wsf[O_MMP + z*512 + 256 + bxy] = mxv;
    }
    if (c < 2) {
      STORECH();       // commit prefetched channel (vmcnt wait lands here)
      __syncthreads(); // xs(c+1) ready
    }
  }
  #undef LOADCH
  #undef STORECH
}

// ---------------- fused min/max fold head + streaming normalization ----------------
// XCD-swizzled to match k_main's sample->XCD mapping (out tiles L2-local).
// Head is barrier/LDS-free: each wave redundantly folds the 128 partials.
__global__ void __launch_bounds__(256)
k_norm(float* __restrict__ out, const float* __restrict__ wsf) {
  int tid = threadIdx.x;
  // bijective XCD swizzle (1536 blocks -> 192-block chunks = 2 samples per XCD)
  int bid = (blockIdx.x & 7) * 192 + (blockIdx.x >> 3);
  int nc = bid >> 5;                 // 32 blocks per (n,c), 2048 f4 each
  int sub = bid & 31;
  int l = tid & 63;
  const float* pm = wsf + O_MMP + (size_t)nc*512;
  float mn = fminf(pm[l], pm[64 + l]);
  float mx = fmaxf(pm[256 + l], pm[320 + l]);
  #pragma unroll
  for (int off = 32; off; off >>= 1) {
    mn = fminf(mn, __shfl_down(mn, off));
    mx = fmaxf(mx, __shfl_down(mx, off));
  }
  mn = __shfl(mn, 0);
  mx = __shfl(mx, 0);
  float sc = 1.0f / (mx - mn + 1e-7f);
  float4* o4 = (float4*)out + (size_t)nc*65536 + (size_t)sub*2048;
  #pragma unroll
  for (int k = 0; k < 8; ++k) {
    float4 v = o4[k*256 + tid];
    v.x = (v.x - mn) * sc; v.y = (v.y - mn) * sc;
    v.z = (v.z - mn) * sc; v.w = (v.w - mn) * sc;
    o4[k*256 + tid] = v;
  }
}

extern "C" void kernel_launch(void* const* d_in, const int* in_sizes, int n_in,
                              void* d_out, int out_size, void* d_ws, size_t ws_size,
                              hipStream_t stream) {
  const float* x  = (const float*)d_in[0];
  const float* o1 = (const float*)d_in[1];
  const float* o2 = (const float*)d_in[2];
  float* out = (float*)d_out;
  float* wsf = (float*)d_ws;
  unsigned* wsu = (unsigned*)d_ws;
  unsigned* hist = (unsigned*)(out + (size_t)16*HW);   // d_out scratch (atomics OK)

  hipMemsetAsync(hist, 0, (size_t)NS*NBIN*sizeof(unsigned), stream);
  k_dark<<<dim3(1024), dim3(512), 0, stream>>>(x, wsf, hist, o1, o2);
  k_asum<<<dim3(512), dim3(256), 0, stream>>>(x, wsf, hist, wsu);
  k_main<<<dim3(2048), dim3(256), 0, stream>>>(x, wsf, wsu, out);
  k_norm<<<dim3(1536), dim3(256), 0, stream>>>(out, wsf);
}

// Round 8
// 154.224 us; speedup vs baseline: 1.0552x; 1.0552x over previous
//
#include <hip/hip_runtime.h>
#include <math.h>

#define NS   16
#define HH   512
#define WW   512
#define HW   (HH*WW)
#define TOPK 13107
#define NBIN 1024

// ---- ws word offsets. NO ATOMICS EVER TARGET d_ws (measured 100+us stalls r1/r2).
// ---- NO cooperative/persistent kernel (measured 1.1ms effective 263 GB/s, r5).
// ---- NO ballot-leader aggregation for smooth value-domain bins (r6: 157us k_dark).
// ---- NO multi-word/float same-address LDS atomics per pixel (r9: 125us k_dark).
// ---- Block-count halving EXHAUSTED at r3 point (r4: +4.8us regression).
// ---- XCD swizzle PROVEN (r5: -6.8us). T14 channel prefetch ~neutral (r6: -0.6us, kept).
// ---- Register-blur (hb elimination) REGRESSED (r7: +8.3us — redundant per-thread
//      LDS reads 2.6x outweigh saved barrier+hb round-trip). hb array is load-bearing.
// ---- FINAL: revert to r6 best-measured structure (154.4us). Converged: no
//      saturated counter, residual is distributed latency; no lever >=2us left.
#define O_O1   0        // [16][7] squashed o1 params   (written k_dark, read k_main)
#define O_O2   112      // [16][4] softmax weights
#define O_DEN  176      // [16]    sum(o2)+0.001
#define O_KN   304      // [16]    remaining k within threshold bin
#define O_MMP  512      // [48][512] per-tile min(0:128)/max(256:384) partials
#define O_PART 25088    // [512][8] asum per-block partials (plain stores only)
#define O_DARK 33280    // [16*512*512] f32 dark channel

// ---- d_out scratch (words; consumed by k_asum before k_main overwrites out):
//   hist = out + 16HW  (16x1024 u32; atomics OK here — d_out, measured fast r2-r4)

// Gaussian weights phi/(sum+0.001), hardcoded (double-derived; ref fp32 diff ~1e-8)
#define G0 0.054466787f
#define G1 0.244103071f
#define G2 0.402457854f

__device__ __forceinline__ float tanh01(float v) { return tanhf(v)*0.5f + 0.5f; }
__device__ __forceinline__ float clamp01(float v) { return fminf(fmaxf(v, 0.0f), 1.0f); }
__device__ __forceinline__ int dark_bin(float v) {
  int b = (int)(v * (float)NBIN);
  return b > (NBIN-1) ? (NBIN-1) : (b < 0 ? 0 : b);
}

// halo load for k_main staging: task i covers xs row i/18, col-quad i%18
__device__ __forceinline__ float4 ld_halo(const float* __restrict__ xc, int i,
                                          int h0, int w0, bool interior) {
  int rr = i / 18, q = i - rr*18;
  int gh = h0 - 2 + rr, gw = w0 - 4 + 4*q;
  if (interior) return *(const float4*)&xc[(size_t)gh*WW + gw];
  float4 v; v.x = 0.f; v.y = 0.f; v.z = 0.f; v.w = 0.f;
  if (gh >= 0 && gh < HH && gw >= 0 && gw < WW)
    v = *(const float4*)&xc[(size_t)gh*WW + gw];
  return v;
}

// ---------------- fused minc + 15x15 box filter + count histogram ----------------
// 1024 blocks (XCD-swizzled), 512 threads: 64x64 dark tile.
__global__ void __launch_bounds__(512)
k_dark(const float* __restrict__ x, float* __restrict__ wsf, unsigned* __restrict__ hist,
       const float* __restrict__ o1, const float* __restrict__ o2) {
  __shared__ __align__(16) float sm[6240 + 78*64];   // union(minc[78*80], lh[1024*4]) + hsum[4992]
  float* minc = sm;
  unsigned* lh = (unsigned*)sm;     // [1024 bins][4 replicas] interleaved
  float* hsum = sm + 6240;
  int tid = threadIdx.x;
  // bijective XCD swizzle (1024 blocks, 8 XCDs -> 128-block contiguous chunks;
  // 128 blocks = 2 full samples of 64 tiles -> same-sample halos L2-local)
  int swz = (blockIdx.x & 7) * 128 + (blockIdx.x >> 3);
  int n = swz >> 6, rem = swz & 63;
  int w0 = (rem & 7) * 64, h0 = (rem >> 3) * 64;
  const float* xb = x + (size_t)n*3*HW;

  // param squashing (one block per sample; hidden under staging; read by k_main)
  if (rem == 0 && tid == 0) {
    wsf[O_O1+n*7+0] = tanh01(o1[n*7+0])*0.25f + 1.0f;
    wsf[O_O1+n*7+1] = tanh01(o1[n*7+1])*0.9f  + 0.1f;
    wsf[O_O1+n*7+2] = tanh01(o1[n*7+2])*2.0f;
    wsf[O_O1+n*7+3] = tanh01(o1[n*7+3]);
    wsf[O_O1+n*7+4] = tanh01(o1[n*7+4])*0.1f + 0.95f;
    wsf[O_O1+n*7+5] = tanh01(o1[n*7+5])*0.1f + 0.95f;
    wsf[O_O1+n*7+6] = tanh01(o1[n*7+6])*0.1f + 0.95f;
    float q0 = expf(tanh01(o2[n*4+0]));
    float q1 = expf(tanh01(o2[n*4+1]));
    float q2 = expf(tanh01(o2[n*4+2]));
    float q3 = expf(tanh01(o2[n*4+3]));
    float s = q0+q1+q2+q3;
    q0 /= s; q1 /= s; q2 /= s; q3 /= s;
    wsf[O_O2+n*4+0]=q0; wsf[O_O2+n*4+1]=q1; wsf[O_O2+n*4+2]=q2; wsf[O_O2+n*4+3]=q3;
    wsf[O_DEN+n] = (q0+q1+q2+q3) + 0.001f;
  }

  // stage minc rows [h0-7,h0+71) cols [w0-8,w0+72), zero outside (box filter zero-pads)
  bool interior = (w0 >= 8) && (w0 + 72 <= WW) && (h0 >= 7) && (h0 + 71 <= HH);
  if (interior) {
    for (int i = tid; i < 78*20; i += 512) {
      int r = i / 20, q = i - r*20;
      size_t o = (size_t)(h0 - 7 + r)*WW + (w0 - 8 + 4*q);
      float4 a = *(const float4*)&xb[o];
      float4 b = *(const float4*)&xb[HW + o];
      float4 c = *(const float4*)&xb[2*HW + o];
      float4 v;
      v.x = fminf(fminf(a.x,b.x),c.x); v.y = fminf(fminf(a.y,b.y),c.y);
      v.z = fminf(fminf(a.z,b.z),c.z); v.w = fminf(fminf(a.w,b.w),c.w);
      *(float4*)&minc[r*80 + 4*q] = v;
    }
  } else {
    for (int i = tid; i < 78*20; i += 512) {
      int r = i / 20, q = i - r*20;
      int hm = h0 - 7 + r, wc = w0 - 8 + 4*q;
      float4 v; v.x = 0.f; v.y = 0.f; v.z = 0.f; v.w = 0.f;
      if (hm >= 0 && hm < HH && wc >= 0 && wc < WW) {
        size_t o = (size_t)hm*WW + wc;
        float4 a = *(const float4*)&xb[o];
        float4 b = *(const float4*)&xb[HW + o];
        float4 c = *(const float4*)&xb[2*HW + o];
        v.x = fminf(fminf(a.x,b.x),c.x); v.y = fminf(fminf(a.y,b.y),c.y);
        v.z = fminf(fminf(a.z,b.z),c.z); v.w = fminf(fminf(a.w,b.w),c.w);
      }
      *(float4*)&minc[r*80 + 4*q] = v;
    }
  }
  __syncthreads();
  // horizontal 15-tap sum
  for (int i = tid; i < 78*16; i += 512) {
    int r = i >> 4, c4 = (i & 15) * 4;
    const float4* mr = (const float4*)&minc[r*80];
    int qb = c4 >> 2;
    float m[20];
    #pragma unroll
    for (int t = 0; t < 5; ++t) {
      float4 v = mr[qb + t];
      m[4*t] = v.x; m[4*t+1] = v.y; m[4*t+2] = v.z; m[4*t+3] = v.w;
    }
    float s = 0.f;
    #pragma unroll
    for (int j = 1; j <= 15; ++j) s += m[j];
    float4 o;
    o.x = s; s += m[16] - m[1];
    o.y = s; s += m[17] - m[2];
    o.z = s; s += m[18] - m[3];
    o.w = s;
    *(float4*)&hsum[r*64 + c4] = o;
  }
  __syncthreads();
  {
    uint4 z4; z4.x = 0u; z4.y = 0u; z4.z = 0u; z4.w = 0u;
    for (int i = tid; i < NBIN; i += 512) ((uint4*)lh)[i] = z4;  // minc dead; reuse
  }
  __syncthreads();
  // vertical 15-tap sliding sum -> dark; run-length + 4-replica LDS atomics
  {
    int c = tid & 63, ty = tid >> 6, r0 = ty * 8;
    int rep = tid & 3;
    float s = 0.f;
    #pragma unroll
    for (int j = 0; j < 15; ++j) s += hsum[(r0 + j)*64 + c];
    float* dk = wsf + O_DARK + (size_t)n*HW;
    int prevb = -1; unsigned cnt = 0;
    #pragma unroll
    for (int i = 0; i < 8; ++i) {
      int r = r0 + i;
      float v = s * (1.0f/225.0f);
      dk[(size_t)(h0 + r)*WW + w0 + c] = v;
      int b = dark_bin(v);
      if (b == prevb) { cnt++; }
      else {
        if (cnt) atomicAdd(&lh[(prevb << 2) | rep], cnt);
        prevb = b; cnt = 1u;
      }
      if (i < 7) s += hsum[(r + 15)*64 + c] - hsum[r*64 + c];
    }
    atomicAdd(&lh[(prevb << 2) | rep], cnt);
  }
  __syncthreads();
  unsigned* gh = hist + n*NBIN;
  for (int b = tid; b < NBIN; b += 512) {
    unsigned v = lh[4*b] + lh[4*b+1] + lh[4*b+2] + lh[4*b+3];
    if (v) atomicAdd(&gh[b], v);
  }
}

// ---------------- fused select head + atmospheric partial sums ----------------
// 512 blocks (XCD-swizzled): 32 chunks x 8192 px per sample.
__global__ void __launch_bounds__(256)
k_asum(const float* __restrict__ x, float* __restrict__ wsf,
       const unsigned* __restrict__ hist, unsigned* __restrict__ wsu) {
  __shared__ __align__(16) unsigned lh[NBIN];
  __shared__ unsigned spp[256];
  __shared__ unsigned wtot[4];
  __shared__ int sh_bsel;
  __shared__ unsigned sh_kn;
  __shared__ float bl[4][7];
  int tid = threadIdx.x;
  int lane = tid & 63, wave = tid >> 6;
  // bijective XCD swizzle (512 blocks -> 64-block chunks = 2 samples per XCD)
  int swz = (blockIdx.x & 7) * 64 + (blockIdx.x >> 3);
  int n = swz >> 5, chunk = swz & 31;
  // select head: load hist (L2-hot) + redundant per-block parallel scan
  {
    uint4 v = ((const uint4*)(hist + n*NBIN))[tid];   // 4 bins per thread
    *(uint4*)&lh[tid*4] = v;
    spp[tid] = v.x + v.y + v.z + v.w;
  }
  __syncthreads();
  // wave-level inclusive suffix scan of spp (suffix = sum over t' >= t)
  unsigned sv = spp[tid];
  #pragma unroll
  for (int off = 1; off < 64; off <<= 1) {
    unsigned u = __shfl_down(sv, off);
    if (lane + off < 64) sv += u;
  }
  if (lane == 0) wtot[wave] = sv;
  __syncthreads();
  unsigned above = 0;
  #pragma unroll
  for (int w2 = 1; w2 < 4; ++w2) above += (wave + w2 < 4) ? wtot[wave + w2] : 0u;
  unsigned S = sv + above;            // inclusive suffix sum at tid
  unsigned Snext = S - spp[tid];      // suffix sum at tid+1
  if (S >= (unsigned)TOPK && Snext < (unsigned)TOPK) {   // unique crossing thread
    unsigned cum = Snext;             // count of pixels in groups above
    int bsel = tid*4;
    for (int b = tid*4 + 3; b >= tid*4; --b) {
      if (cum + lh[b] >= (unsigned)TOPK) { bsel = b; break; }
      cum += lh[b];
    }
    sh_bsel = bsel;
    sh_kn = (unsigned)TOPK - cum;
  }
  __syncthreads();
  int bsel = sh_bsel;
  if (tid == 0 && chunk == 0) wsu[O_KN + n] = sh_kn;   // plain store to ws
  // partial sums over this 8192-element chunk; x loads PREDICATED on dark bin
  // (dark is 15x15-box smooth -> selected ~5% clustered -> most waves skip via execz)
  const float4* db = (const float4*)(wsf + O_DARK + (size_t)n*HW) + (size_t)chunk*2048;
  const float4* x0 = (const float4*)(x + (size_t)n*3*HW) + (size_t)chunk*2048;
  const float4* x1 = x0 + HW/4;
  const float4* x2 = x0 + HW/2;
  float s0=0,s1=0,s2=0,e0=0,e1=0,e2=0,ec=0;
  #pragma unroll
  for (int k = 0; k < 8; ++k) {
    int idx = k*256 + tid;
    float4 d = db[idx];
    int bbx = dark_bin(d.x), bby = dark_bin(d.y);
    int bbz = dark_bin(d.z), bbw = dark_bin(d.w);
    int bmax = bbx > bby ? bbx : bby;
    bmax = bbz > bmax ? bbz : bmax;
    bmax = bbw > bmax ? bbw : bmax;
    if (bmax >= bsel) {
      float4 a = x0[idx], b = x1[idx], c = x2[idx];
      #define ACC(BB, AX, BX, CX) { \
        bool gt = (BB > bsel), eq = (BB == bsel); \
        s0 += gt ? AX : 0.f; s1 += gt ? BX : 0.f; s2 += gt ? CX : 0.f; \
        e0 += eq ? AX : 0.f; e1 += eq ? BX : 0.f; e2 += eq ? CX : 0.f; \
        ec += eq ? 1.f : 0.f; }
      ACC(bbx, a.x, b.x, c.x) ACC(bby, a.y, b.y, c.y)
      ACC(bbz, a.z, b.z, c.z) ACC(bbw, a.w, b.w, c.w)
      #undef ACC
    }
  }
  #pragma unroll
  for (int off = 32; off; off >>= 1) {
    s0 += __shfl_down(s0, off); s1 += __shfl_down(s1, off); s2 += __shfl_down(s2, off);
    e0 += __shfl_down(e0, off); e1 += __shfl_down(e1, off); e2 += __shfl_down(e2, off);
    ec += __shfl_down(ec, off);
  }
  if (lane == 0) {
    bl[wave][0]=s0; bl[wave][1]=s1; bl[wave][2]=s2;
    bl[wave][3]=e0; bl[wave][4]=e1; bl[wave][5]=e2; bl[wave][6]=ec;
  }
  __syncthreads();
  if (tid < 7) wsf[O_PART + (size_t)swz*8 + tid] =
      bl[0][tid] + bl[1][tid] + bl[2][tid] + bl[3][tid];   // plain store to ws
}

// ---------------- fused per-pixel kernel: 64x32 tile, 2 rows/thread ----------------
// 2048 blocks (XCD-swizzled), 256 threads; channels pipelined: ch c+1 is
// prefetched into registers during ch c's compute, committed to LDS after the
// barrier that frees xs (T14 async-stage split — hides stage latency).
__global__ void __launch_bounds__(256)
k_main(const float* __restrict__ x, float* __restrict__ wsf,
       const unsigned* __restrict__ wsu, float* __restrict__ out) {
  __shared__ __align__(16) float xs[36*72];   // rows h0-2..h0+33, cols w0-4..w0+67
  __shared__ __align__(16) float hb[36*68];   // horizontal blur, stride 68 (bank-pad)
  __shared__ float rmn[4], rmx[4];
  __shared__ float shA[3];
  int tid = threadIdx.x;
  // bijective XCD swizzle (2048 blocks -> 256-block chunks = 2 samples per XCD)
  int swz = (blockIdx.x & 7) * 256 + (blockIdx.x >> 3);
  int n = swz >> 7, bxy = swz & 127;           // [0,128)
  int w0 = (bxy & 7) * 64, h0 = (bxy >> 3) * 32;
  int r2 = tid >> 4, c4 = (tid & 15) * 4;      // thread owns rows 2r2, 2r2+1
  int wave = tid >> 6, lane = tid & 63;
  const float* dkp = wsf + O_DARK + (size_t)n*HW + (size_t)(h0 + 2*r2)*WW + w0 + c4;
  float4 dk0 = *(const float4*)dkp;
  float4 dk1 = *(const float4*)(dkp + WW);
  float param = wsf[O_O1 + n*7 + 0];
  float lamda = wsf[O_O1 + n*7 + 2];
  float wpar  = wsf[O_O1 + n*7 + 3];
  float wbc[3];
  wbc[0] = wsf[O_O1 + n*7 + 4];
  wbc[1] = wsf[O_O1 + n*7 + 5];
  wbc[2] = wsf[O_O1 + n*7 + 6];
  float q0 = wsf[O_O2 + n*4 + 0], q1 = wsf[O_O2 + n*4 + 1];
  float q2 = wsf[O_O2 + n*4 + 2], q3 = wsf[O_O2 + n*4 + 3];
  float rden = 1.0f / wsf[O_DEN + n];
  bool interior = (w0 >= 4) && (w0 + 68 <= WW) && (h0 >= 2) && (h0 + 34 <= HH);
  // A-reduce head (once per block, all 3 channels; 32 partial-sets from k_asum)
  if (tid < 64) {
    float s0=0,s1=0,s2=0,e0=0,e1=0,e2=0,ec=0;
    if (tid < 32) {
      const float* p = wsf + O_PART + (size_t)(n*32 + tid)*8;
      s0=p[0]; s1=p[1]; s2=p[2]; e0=p[3]; e1=p[4]; e2=p[5]; ec=p[6];
    }
    #pragma unroll
    for (int off = 32; off; off >>= 1) {
      s0 += __shfl_down(s0, off); s1 += __shfl_down(s1, off); s2 += __shfl_down(s2, off);
      e0 += __shfl_down(e0, off); e1 += __shfl_down(e1, off); e2 += __shfl_down(e2, off);
      ec += __shfl_down(ec, off);
    }
    if (tid == 0) {
      float kn = (float)wsu[O_KN + n];
      float ce = fmaxf(ec, 1.0f);
      shA[0] = (s0 + kn * (e0 / ce)) * (1.0f/(float)TOPK);
      shA[1] = (s1 + kn * (e1 / ce)) * (1.0f/(float)TOPK);
      shA[2] = (s2 + kn * (e2 / ce)) * (1.0f/(float)TOPK);
    }
  }

  // staging register set (648 tasks: tid, tid+256, tid+512 if tid<136)
  float4 pf0, pf1, pf2;
  #define LOADCH(cc) do { \
    const float* xc = x + (size_t)(n*3 + (cc))*HW; \
    pf0 = ld_halo(xc, tid,       h0, w0, interior); \
    pf1 = ld_halo(xc, tid + 256, h0, w0, interior); \
    if (tid < 136) pf2 = ld_halo(xc, tid + 512, h0, w0, interior); \
  } while (0)
  #define STORECH() do { \
    { int rr = tid/18, q = tid - rr*18; *(float4*)&xs[rr*72 + 4*q] = pf0; } \
    { int i2 = tid + 256; int rr = i2/18, q = i2 - rr*18; *(float4*)&xs[rr*72 + 4*q] = pf1; } \
    if (tid < 136) { int i2 = tid + 512; int rr = i2/18, q = i2 - rr*18; *(float4*)&xs[rr*72 + 4*q] = pf2; } \
  } while (0)

  // prologue: stage channel 0
  LOADCH(0);
  STORECH();
  __syncthreads();   // xs(c0) ready; also covers shA write

  for (int c = 0; c < 3; ++c) {
    int z = n*3 + c;
    // horizontal blur (reads xs, writes hb)
    for (int i = tid; i < 576; i += 256) {
      int rr = i >> 4, cc4 = (i & 15) * 4;
      const float4* xr = (const float4*)&xs[rr*72];
      int qb = cc4 >> 2;
      float4 A4 = xr[qb], B4 = xr[qb+1], C4 = xr[qb+2];
      float m2=A4.z, m3=A4.w, m4=B4.x, m5=B4.y, m6=B4.z, m7=B4.w, m8=C4.x, m9=C4.y;
      float4 o;
      o.x = G0*(m2+m6) + G1*(m3+m5) + G2*m4;
      o.y = G0*(m3+m7) + G1*(m4+m6) + G2*m5;
      o.z = G0*(m4+m8) + G1*(m5+m7) + G2*m6;
      o.w = G0*(m5+m9) + G1*(m6+m8) + G2*m7;
      *(float4*)&hb[rr*68 + cc4] = o;
    }
    // issue next channel's staging loads (latency hides under pixel phase)
    if (c < 2) LOADCH(c + 1);
    __syncthreads();   // hb ready
    float wb = wbc[c];
    float A  = shA[c];
    float4 xv0 = *(const float4*)&xs[(2*r2+2)*72 + c4 + 4];
    float4 xv1 = *(const float4*)&xs[(2*r2+3)*72 + c4 + 4];
    float4 b0 = *(const float4*)&hb[(2*r2+0)*68 + c4];
    float4 b1 = *(const float4*)&hb[(2*r2+1)*68 + c4];
    float4 b2 = *(const float4*)&hb[(2*r2+2)*68 + c4];
    float4 b3 = *(const float4*)&hb[(2*r2+3)*68 + c4];
    float4 b4 = *(const float4*)&hb[(2*r2+4)*68 + c4];
    float4 b5 = *(const float4*)&hb[(2*r2+5)*68 + c4];
    float4 os0, os1;
    float mnv = 3.4e38f, mxv = -3.4e38f;
    #define PIX(OX, XV, B0, B1, B2, B3, B4, DK) { \
      float blur = clamp01(G0*(B0+B4) + G1*(B1+B3) + G2*B2); \
      float x4v = clamp01(XV + lamda*(XV - blur)); \
      float x1v = clamp01(XV * wb); \
      float x2v = clamp01(__expf(param*__logf(XV)) + 0.001f); \
      float tr = 1.0f - wpar*DK; tr = tr > 0.1f ? tr : 0.1f; \
      float x5v = clamp01((XV - A) * __builtin_amdgcn_rcpf(tr + 0.001f) + A); \
      OX = (XV + 0.1f*(q0*x1v + q1*x2v + q2*x4v + q3*x5v)) * rden; \
      mnv = fminf(mnv, OX); mxv = fmaxf(mxv, OX); }
    PIX(os0.x, xv0.x, b0.x, b1.x, b2.x, b3.x, b4.x, dk0.x)
    PIX(os0.y, xv0.y, b0.y, b1.y, b2.y, b3.y, b4.y, dk0.y)
    PIX(os0.z, xv0.z, b0.z, b1.z, b2.z, b3.z, b4.z, dk0.z)
    PIX(os0.w, xv0.w, b0.w, b1.w, b2.w, b3.w, b4.w, dk0.w)
    PIX(os1.x, xv1.x, b1.x, b2.x, b3.x, b4.x, b5.x, dk1.x)
    PIX(os1.y, xv1.y, b1.y, b2.y, b3.y, b4.y, b5.y, dk1.y)
    PIX(os1.z, xv1.z, b1.z, b2.z, b3.z, b4.z, b5.z, dk1.z)
    PIX(os1.w, xv1.w, b1.w, b2.w, b3.w, b4.w, b5.w, dk1.w)
    #undef PIX
    float* op = out + (size_t)z*HW + (size_t)(h0 + 2*r2)*WW + w0 + c4;
    *(float4*)op = os0;
    *(float4*)(op + WW) = os1;
    #pragma unroll
    for (int off = 32; off; off >>= 1) {
      mnv = fminf(mnv, __shfl_down(mnv, off));
      mxv = fmaxf(mxv, __shfl_down(mxv, off));
    }
    if (lane == 0) { rmn[wave] = mnv; rmx[wave] = mxv; }
    __syncthreads();   // xs/hb consumers done; rmn/rmx ready
    if (tid == 0) {
      mnv = fminf(fminf(rmn[0], rmn[1]), fminf(rmn[2], rmn[3]));
      mxv = fmaxf(fmaxf(rmx[0], rmx[1]), fmaxf(rmx[2], rmx[3]));
      wsf[O_MMP + z*512 + bxy]       = mnv;   // plain stores to ws
      wsf[O_MMP + z*512 + 256 + bxy] = mxv;
    }
    if (c < 2) {
      STORECH();       // commit prefetched channel (vmcnt wait lands here)
      __syncthreads(); // xs(c+1) ready for next hblur
    }
  }
  #undef LOADCH
  #undef STORECH
}

// ---------------- fused min/max fold head + streaming normalization ----------------
// XCD-swizzled to match k_main's sample->XCD mapping (out tiles L2-local).
// Head is barrier/LDS-free: each wave redundantly folds the 128 partials.
__global__ void __launch_bounds__(256)
k_norm(float* __restrict__ out, const float* __restrict__ wsf) {
  int tid = threadIdx.x;
  // bijective XCD swizzle (1536 blocks -> 192-block chunks = 2 samples per XCD)
  int bid = (blockIdx.x & 7) * 192 + (blockIdx.x >> 3);
  int nc = bid >> 5;                 // 32 blocks per (n,c), 2048 f4 each
  int sub = bid & 31;
  int l = tid & 63;
  const float* pm = wsf + O_MMP + (size_t)nc*512;
  float mn = fminf(pm[l], pm[64 + l]);
  float mx = fmaxf(pm[256 + l], pm[320 + l]);
  #pragma unroll
  for (int off = 32; off; off >>= 1) {
    mn = fminf(mn, __shfl_down(mn, off));
    mx = fmaxf(mx, __shfl_down(mx, off));
  }
  mn = __shfl(mn, 0);
  mx = __shfl(mx, 0);
  float sc = 1.0f / (mx - mn + 1e-7f);
  float4* o4 = (float4*)out + (size_t)nc*65536 + (size_t)sub*2048;
  #pragma unroll
  for (int k = 0; k < 8; ++k) {
    float4 v = o4[k*256 + tid];
    v.x = (v.x - mn) * sc; v.y = (v.y - mn) * sc;
    v.z = (v.z - mn) * sc; v.w = (v.w - mn) * sc;
    o4[k*256 + tid] = v;
  }
}

extern "C" void kernel_launch(void* const* d_in, const int* in_sizes, int n_in,
                              void* d_out, int out_size, void* d_ws, size_t ws_size,
                              hipStream_t stream) {
  const float* x  = (const float*)d_in[0];
  const float* o1 = (const float*)d_in[1];
  const float* o2 = (const float*)d_in[2];
  float* out = (float*)d_out;
  float* wsf = (float*)d_ws;
  unsigned* wsu = (unsigned*)d_ws;
  unsigned* hist = (unsigned*)(out + (size_t)16*HW);   // d_out scratch (atomics OK)

  hipMemsetAsync(hist, 0, (size_t)NS*NBIN*sizeof(unsigned), stream);
  k_dark<<<dim3(1024), dim3(512), 0, stream>>>(x, wsf, hist, o1, o2);
  k_asum<<<dim3(512), dim3(256), 0, stream>>>(x, wsf, hist, wsu);
  k_main<<<dim3(2048), dim3(256), 0, stream>>>(x, wsf, wsu, out);
  k_norm<<<dim3(1536), dim3(256), 0, stream>>>(out, wsf);
}